// Round 6
// baseline (432.902 us; speedup 1.0000x reference)
//
#include <hip/hip_runtime.h>

// Problem constants (from reference)
#define NPTS 32768
#define DIM  64
#define NCLS 50
#define NH   5
#define NW1  6            // windows + frame
#define NBOX (NH * NW1)   // 30 boxes per class
#define PPT  2            // points per thread
#define HALF (NPTS / PPT) // 16384

// d_out layout: [ data: NPTS*DIM ][ contains: NCLS*NPTS ][ dists: NCLS*NH*NW1*NPTS ]
#define DATA_ELEMS   (NPTS * DIM)
#define CONT_ELEMS   (NCLS * NPTS)
#define DIST_OFFSET  (DATA_ELEMS + CONT_ELEMS)

typedef _Float16 h2 __attribute__((ext_vector_type(2)));

// Pass-through copy of `data` (avoids in-graph SDMA memcpy, which may be slow).
__global__ __launch_bounds__(256) void copy_k(const float4* __restrict__ in,
                                              float4* __restrict__ out) {
    const int i = blockIdx.x * 256 + threadIdx.x;
    out[i] = in[i];
}

// prep_k: sort corners to lo/hi and convert to packed f16 pairs in d_ws.
// Per box (c,b): 64 dwords = [ 32 x lo-pair(h2) | 32 x hi-pair(h2) ] = 256 B.
__global__ __launch_bounds__(64) void prep_k(const float* __restrict__ shape,
                                             unsigned* __restrict__ ws) {
    const int b = blockIdx.x;       // box 0..29
    const int c = blockIdx.y;       // class 0..49
    const int t = threadIdx.x;      // 0..63
    const int j = t & 31;           // dim pair 0..31
    const bool hiPart = t >= 32;
    const float* src = shape + (size_t)(c * NBOX + b) * 2 * DIM;
    const float a0 = src[2 * j],       a1 = src[2 * j + 1];
    const float e0 = src[DIM + 2 * j], e1 = src[DIM + 2 * j + 1];
    const float v0 = hiPart ? fmaxf(a0, e0) : fminf(a0, e0);
    const float v1 = hiPart ? fmaxf(a1, e1) : fminf(a1, e1);
    h2 h; h.x = (_Float16)v0; h.y = (_Float16)v1;
    ws[(size_t)(c * NBOX + b) * 64 + (hiPart ? 32 : 0) + j] =
        __builtin_bit_cast(unsigned, h);
}

// geom_k: one thread per (2 points, class). Box bounds arrive wave-uniform via
// scalar loads (SGPRs, 256 B/box shared by both points); per 2 dims per point:
// v_pk_add(neg) x2, v_pk_max x2, v_dot2_f32_f16 = 2.5 VALU/dim with f32 accum.
// 2 points/thread halves the SMEM-stall : compute ratio vs 1 point/thread.
__global__ __launch_bounds__(256) void geom_k(const float* __restrict__ data,
                                              const h2* __restrict__ box,
                                              float* __restrict__ out) {
    const int c = blockIdx.y;
    const int n = blockIdx.x * 256 + threadIdx.x;      // first point
    // second point: n + HALF (keeps both loads/stores lane-coalesced)

    h2 pa[DIM / 2], pb[DIM / 2];
    {
        const float4* va = reinterpret_cast<const float4*>(data + (size_t)n * DIM);
        const float4* vb = reinterpret_cast<const float4*>(data + (size_t)(n + HALF) * DIM);
#pragma unroll
        for (int k = 0; k < DIM / 4; ++k) {
            const float4 x = va[k];
            h2 u, w;
            u.x = (_Float16)x.x; u.y = (_Float16)x.y;
            w.x = (_Float16)x.z; w.y = (_Float16)x.w;
            pa[2 * k] = u; pa[2 * k + 1] = w;
            const float4 y = vb[k];
            u.x = (_Float16)y.x; u.y = (_Float16)y.y;
            w.x = (_Float16)y.z; w.y = (_Float16)y.w;
            pb[2 * k] = u; pb[2 * k + 1] = w;
        }
    }

    float* distOut = out + DIST_OFFSET + (size_t)c * (NBOX * NPTS) + n;

    unsigned townA = 0u, townB = 0u;
#pragma unroll 1
    for (int h = 0; h < NH; ++h) {
        unsigned anyWinA = 0u, frameA = 0u;
        unsigned anyWinB = 0u, frameB = 0u;
#pragma unroll 1
        for (int w = 0; w < NW1; ++w) {
            const int b = h * NW1 + w;
            const h2* bb = box + (size_t)(c * NBOX + b) * 64;  // wave-uniform
            float sa0 = 0.f, sa1 = 0.f, sb0 = 0.f, sb1 = 0.f;  // 4 dot2 chains
#pragma unroll
            for (int i = 0; i < 32; i += 2) {
                const h2 lo0 = bb[i],     hi0 = bb[32 + i];
                const h2 lo1 = bb[i + 1], hi1 = bb[33 + i];
                // point A
                h2 m0 = __builtin_elementwise_max(lo0 - pa[i], pa[i] - hi0);
                m0 = __builtin_elementwise_max(m0, (h2)(_Float16)0);
                sa0 = __builtin_amdgcn_fdot2(m0, m0, sa0, false);
                h2 m1 = __builtin_elementwise_max(lo1 - pa[i + 1], pa[i + 1] - hi1);
                m1 = __builtin_elementwise_max(m1, (h2)(_Float16)0);
                sa1 = __builtin_amdgcn_fdot2(m1, m1, sa1, false);
                // point B
                h2 m2 = __builtin_elementwise_max(lo0 - pb[i], pb[i] - hi0);
                m2 = __builtin_elementwise_max(m2, (h2)(_Float16)0);
                sb0 = __builtin_amdgcn_fdot2(m2, m2, sb0, false);
                h2 m3 = __builtin_elementwise_max(lo1 - pb[i + 1], pb[i + 1] - hi1);
                m3 = __builtin_elementwise_max(m3, (h2)(_Float16)0);
                sb1 = __builtin_amdgcn_fdot2(m3, m3, sb1, false);
            }
            const float sqA = sa0 + sa1;
            const float sqB = sb0 + sb1;
            distOut[(size_t)b * NPTS] = __builtin_amdgcn_sqrtf(sqA);
            distOut[(size_t)b * NPTS + HALF] = __builtin_amdgcn_sqrtf(sqB);
            const unsigned inA = (sqA == 0.f) ? 1u : 0u;   // inside <=> sq == 0
            const unsigned inB = (sqB == 0.f) ? 1u : 0u;
            if (w < NW1 - 1) { anyWinA |= inA; anyWinB |= inB; }
            else             { frameA = inA;   frameB = inB; }
        }
        townA |= (frameA & (anyWinA ^ 1u));
        townB |= (frameB & (anyWinB ^ 1u));
    }
    out[DATA_ELEMS + (size_t)c * NPTS + n] = townA ? 1.0f : 0.0f;
    out[DATA_ELEMS + (size_t)c * NPTS + n + HALF] = townB ? 1.0f : 0.0f;
}

extern "C" void kernel_launch(void* const* d_in, const int* in_sizes, int n_in,
                              void* d_out, int out_size, void* d_ws, size_t ws_size,
                              hipStream_t stream) {
    const float* data  = (const float*)d_in[0];   // [32768,64] f32
    const float* shape = (const float*)d_in[1];   // [50,5,6,2,64] f32
    float* out = (float*)d_out;
    unsigned* ws = (unsigned*)d_ws;               // needs 50*30*64*4 = 384 KB

    // Output 0: pass-through copy of data (kernel, not SDMA).
    copy_k<<<DATA_ELEMS / 4 / 256, 256, 0, stream>>>(
        (const float4*)data, (float4*)out);

    // Precompute packed-f16 lo/hi box bounds into workspace.
    prep_k<<<dim3(NBOX, NCLS), 64, 0, stream>>>(shape, ws);

    // Main geometry kernel: 2 points per thread.
    geom_k<<<dim3(HALF / 256, NCLS), 256, 0, stream>>>(
        data, (const h2*)ws, out);
}